// Round 10
// baseline (171582.812 us; speedup 1.0000x reference)
//
#include <hip/hip_runtime.h>

#define TSTEPS 1024
#define BB 128
#define HH 512
#define NCH 80
#define NATT 10
#define NG 20
#define UU 64
#define LOG2PI 1.8378770664093453f

// ws float offsets
#define OFF_HA0 0
#define OFF_HA1 65536
#define OFF_WT0 131072
#define OFF_WT1 141312
#define OFF_RED 151552
#define OFF_EP  151808      // h_ep[256]*16 | w_ep[128]*16 | red_cnt
#define EP_WORDS (256*16 + 128*16 + 16)

static __device__ __forceinline__ float ld_scf(const float* p) {
    return __hip_atomic_load((float*)p, __ATOMIC_RELAXED, __HIP_MEMORY_SCOPE_AGENT);
}
static __device__ __forceinline__ void st_scf(float* p, float v) {
    __hip_atomic_store(p, v, __ATOMIC_RELAXED, __HIP_MEMORY_SCOPE_AGENT);
}
static __device__ __forceinline__ float2 ld_sc2(const float* p) {
    unsigned long long v = __hip_atomic_load((unsigned long long*)p, __ATOMIC_RELAXED, __HIP_MEMORY_SCOPE_AGENT);
    float2 f; __builtin_memcpy(&f, &v, 8); return f;
}
static __device__ __forceinline__ unsigned ld_u(const unsigned* p) {
    return __hip_atomic_load((unsigned*)p, __ATOMIC_RELAXED, __HIP_MEMORY_SCOPE_AGENT);
}
static __device__ __forceinline__ void st_u(unsigned* p, unsigned v) {
    __hip_atomic_store(p, v, __ATOMIC_RELAXED, __HIP_MEMORY_SCOPE_AGENT);
}

__global__ void init_sync_kernel(float* ws) {
    unsigned* s = (unsigned*)(ws + OFF_EP);
    for (int i = threadIdx.x; i < EP_WORDS; i += blockDim.x) st_u(s + i, 0u);
}

__global__ __launch_bounds__(512)
void hw_kernel(const float* __restrict__ seq_pt, const float* __restrict__ seq_mask,
               const float* __restrict__ tgt, const int* __restrict__ cidx,
               const float* __restrict__ c_mask,
               const float* __restrict__ W_ih, const float* __restrict__ b_ih,
               const float* __restrict__ W_hh, const float* __restrict__ b_hh,
               const float* __restrict__ W_att, const float* __restrict__ b_att,
               const float* __restrict__ W_mix, const float* __restrict__ b_mix,
               float* __restrict__ out, float* __restrict__ ws)
{
    const int g = blockIdx.x;
    const int tid = threadIdx.x;
    const int jblk = g >> 2;            // 0..63
    const int bblk = g & 3;             // 0..3
    const int gb0 = bblk * 32;
    const bool isAttn = (jblk < 32);
    const int pbcol = isAttn ? jblk : (jblk - 32);
    const int pb = gb0 + pbcol;
    const int jj  = tid & 7;
    const int bg3 = (tid >> 3) & 7;
    const int ks  = tid >> 6;           // wave index (0..7) = d-split

    __shared__ float4 s_wW[8][601];                 // 76.9 KB gate weights
    __shared__ __align__(16) float s_h[16384];      // 64 KB h tile [512][32]; overlays: w[80][32]@0, partials@2560
    __shared__ float s_hcol[512];
    __shared__ float s_pA[512];
    __shared__ float s_wp[84];
    __shared__ float s_yh[124], s_y[124];
    __shared__ float s_ab[72];                      // att raw 0..29 | alpha@32 beta@42 kn@52
    __shared__ float s_kk[16], s_wold[NCH], s_phi[UU];
    __shared__ int   s_ci[UU];
    __shared__ float s_nA[20], s_nB[20], s_pen[1];

    // ---- persistent LDS gate weights ----
    for (int lin = tid; lin < 8 * 596; lin += 512) {
        int lj = lin / 596, idx = lin % 596;
        int jg = jblk * 8 + lj;
        float4 v;
        if (idx < 512) {
            v = make_float4(W_hh[(0 * HH + jg) * HH + idx], W_hh[(1 * HH + jg) * HH + idx],
                            W_hh[(2 * HH + jg) * HH + idx], W_hh[(3 * HH + jg) * HH + idx]);
        } else if (idx < 592) {
            int dd = 3 + (idx - 512);
            v = make_float4(W_ih[(0 * HH + jg) * 83 + dd], W_ih[(1 * HH + jg) * 83 + dd],
                            W_ih[(2 * HH + jg) * 83 + dd], W_ih[(3 * HH + jg) * 83 + dd]);
        } else if (idx < 595) {
            int dd = idx - 592;
            v = make_float4(W_ih[(0 * HH + jg) * 83 + dd], W_ih[(1 * HH + jg) * 83 + dd],
                            W_ih[(2 * HH + jg) * 83 + dd], W_ih[(3 * HH + jg) * 83 + dd]);
        } else {
            v = make_float4(b_ih[0 * HH + jg] + b_hh[0 * HH + jg], b_ih[1 * HH + jg] + b_hh[1 * HH + jg],
                            b_ih[2 * HH + jg] + b_hh[2 * HH + jg], b_ih[3 * HH + jg] + b_hh[3 * HH + jg]);
        }
        s_wW[lj][idx] = v;
    }
    if (isAttn && tid < UU) s_ci[tid] = cidx[(size_t)tid * BB + pb];
    if (tid < 16) s_kk[tid] = 0.f;
    if (tid < NCH) s_wold[tid] = 0.f;

    // ---- preload W_att fragment into registers (attention WGs) ----
    float4 wa[8];
    {
        int m = tid & 31, seg = tid >> 5;
        if (isAttn && m < 30) {
            #pragma unroll
            for (int q = 0; q < 8; ++q)
                wa[q] = *(const float4*)(W_att + (size_t)m * HH + seg * 32 + q * 4);
        } else {
            #pragma unroll
            for (int q = 0; q < 8; ++q) wa[q] = make_float4(0.f, 0.f, 0.f, 0.f);
        }
    }
    __syncthreads();

    unsigned* h_ep = (unsigned*)(ws + OFF_EP);
    unsigned* w_ep = h_ep + 256 * 16;
    unsigned* red_cnt = w_ep + 128 * 16;
    float* red = ws + OFF_RED;
    float* s_w = s_h;                 // overlay [80][32]
    float* s_part = s_h + 2560;       // overlay partials [512][20]

    float cell = 0.f, nll_acc = 0.f, mask_acc = 0.f;
    unsigned esampH = 0;
    float2 hr[16];                    // staged h(t) for phase A(t+1), issued in phase B(t)

    auto FMA4 = [](float4& acc, float h, float4 w) {
        acc.x = fmaf(h, w.x, acc.x); acc.y = fmaf(h, w.y, acc.y);
        acc.z = fmaf(h, w.z, acc.z); acc.w = fmaf(h, w.w, acc.w);
    };

    // NLL(tp) on mixture WGs: uses s_yh = yh(tp) (local) and s_wp = w(tp)
    auto do_nll = [&](int tp) {
        if (tid < 121) {
            const float* wm = W_mix + (size_t)tid * 592 + 512;
            float acc = s_yh[tid] + b_mix[tid];
            #pragma unroll 8
            for (int c = 0; c < NCH; ++c) acc = fmaf(s_wp[c], wm[c], acc);
            s_y[tid] = acc;
        }
        __syncthreads();
        if (tid < 21) {
            const float* tg = tgt + ((size_t)tp * BB + pb) * 3;
            if (tid < NG) {
                int m = tid;
                float y0 = s_y[m], y1 = s_y[20 + m], y2 = s_y[40 + m];
                float y3 = s_y[60 + m], y4 = s_y[80 + m], y5 = s_y[100 + m];
                float x1 = tg[0], x2 = tg[1];
                float rho = tanhf(y5);
                float d1 = (x1 - y1) * expf(-y3);
                float d2 = (x2 - y2) * expf(-y4);
                float omr2 = 1.f - rho * rho;
                float Z = d1 * d1 + d2 * d2 - 2.f * rho * d1 * d2;
                float log_n = -Z / (2.f * omr2) - LOG2PI - y3 - y4 - 0.5f * logf(omr2);
                s_nA[m] = y0;
                s_nB[m] = y0 + log_n;
            } else {
                float yp = s_y[120];
                float pen = tg[2];
                float e = log1pf(expf(-fabsf(yp)));
                float ls_p = fminf(yp, 0.f) - e;
                float ls_n = fminf(-yp, 0.f) - e;
                s_pen[0] = -(pen * ls_p + (1.f - pen) * ls_n);
            }
        }
        __syncthreads();
        if (tid == 0) {
            float mx1 = -1e30f, mx2 = -1e30f;
            for (int m = 0; m < NG; ++m) { mx1 = fmaxf(mx1, s_nA[m]); mx2 = fmaxf(mx2, s_nB[m]); }
            float se1 = 0.f, se2 = 0.f;
            for (int m = 0; m < NG; ++m) { se1 += expf(s_nA[m] - mx1); se2 += expf(s_nB[m] - mx2); }
            float nll = (mx1 + logf(se1)) - (mx2 + logf(se2)) + s_pen[0];
            float mk = seq_mask[(size_t)tp * BB + pb];
            nll_acc += mk * nll;
            mask_acc += mk;
        }
        __syncthreads();
    };

    for (int t = 0; t < TSTEPS; ++t) {
        float* hAcur = ws + ((t & 1) ? OFF_HA1 : OFF_HA0);

        float4 a0 = make_float4(0.f,0.f,0.f,0.f), a1 = a0, a2 = a0, a3 = a0;
        auto fmaBlk = [&](int r) {
            #pragma unroll
            for (int i = 0; i < 8; ++i) {
                int dl = r * 64 + ks * 8 + i;
                float4 gw = s_wW[jj][dl];
                float4 hv = *(const float4*)&s_h[dl * 32 + bg3 * 4];
                FMA4(a0, hv.x, gw); FMA4(a1, hv.y, gw);
                FMA4(a2, hv.z, gw); FMA4(a3, hv.w, gw);
            }
        };

        // ================= phase A(t) =================
        if (t > 0) {
            const float* wTp = ws + (((t - 1) & 1) ? OFF_WT1 : OFF_WT0);
            // write staged h(t-1) (loads were issued in phase B(t-1); regs force the wait)
            #pragma unroll
            for (int i = 0; i < 16; ++i) {
                int lin = i * 512 + tid, d = lin >> 4, c2 = lin & 15;
                *(float2*)&s_h[d * 32 + c2 * 2] = hr[i];
            }
            __syncthreads();
            fmaBlk(0); fmaBlk(1); fmaBlk(2); fmaBlk(3);
            // w(t-1) wait (published end of phase B(t-1); normally satisfied)
            if (tid < 32) {
                const unsigned* p = w_ep + (bblk * 32 + tid) * 16;
                while (ld_u(p) < (unsigned)t) __builtin_amdgcn_s_sleep(1);
            }
            __syncthreads();
            asm volatile("" ::: "memory");
            float2 wr2[3];
            #pragma unroll
            for (int i = 0; i < 3; ++i) {
                int lin = i * 512 + tid;
                if (lin < 1280) {
                    int c = lin >> 4, c2 = lin & 15;
                    wr2[i] = ld_sc2(wTp + (size_t)c * BB + gb0 + c2 * 2);
                }
            }
            fmaBlk(4); fmaBlk(5); fmaBlk(6); fmaBlk(7);   // covers w-load latency
            __syncthreads();                               // all h-tile reads done
            #pragma unroll
            for (int i = 0; i < 3; ++i) {
                int lin = i * 512 + tid;
                if (lin < 1280) {
                    int c = lin >> 4, c2 = lin & 15;
                    *(float2*)&s_w[c * 32 + c2 * 2] = wr2[i];
                }
            }
            __syncthreads();
            #pragma unroll
            for (int i = 0; i < 10; ++i) {
                int c = ks * 10 + i;
                float4 gw = s_wW[jj][512 + c];
                float4 wv = *(const float4*)&s_w[c * 32 + bg3 * 4];
                FMA4(a0, wv.x, gw); FMA4(a1, wv.y, gw);
                FMA4(a2, wv.z, gw); FMA4(a3, wv.w, gw);
            }
            {   // partial exchange, pitch-20
                int R = ((ks * 8 + jj) * 8 + bg3);
                *(float4*)&s_part[R * 20 + 0]  = a0;
                *(float4*)&s_part[R * 20 + 4]  = a1;
                *(float4*)&s_part[R * 20 + 8]  = a2;
                *(float4*)&s_part[R * 20 + 12] = a3;
            }
            __syncthreads();
        }

        // pointwise LSTM + publish h(t)
        if (tid < 256) {
            int jj_o = tid >> 5, bl = tid & 31;
            int b = gb0 + bl, j = jblk * 8 + jj_o;
            float4 s = s_wW[jj_o][595];   // fused bias
            if (t > 0) {
                #pragma unroll
                for (int k2 = 0; k2 < 8; ++k2) {
                    int Rr = ((k2 * 8 + jj_o) * 8 + (bl >> 2));
                    float4 v = *(const float4*)&s_part[Rr * 20 + (bl & 3) * 4];
                    s.x += v.x; s.y += v.y; s.z += v.z; s.w += v.w;
                }
            }
            const float* ip = seq_pt + ((size_t)t * BB + b) * 3;
            float x0 = ip[0], x1 = ip[1], x2 = ip[2];
            float4 wx0 = s_wW[jj_o][592], wx1 = s_wW[jj_o][593], wx2 = s_wW[jj_o][594];
            s.x += x0 * wx0.x + x1 * wx1.x + x2 * wx2.x;
            s.y += x0 * wx0.y + x1 * wx1.y + x2 * wx2.y;
            s.z += x0 * wx0.z + x1 * wx1.z + x2 * wx2.z;
            s.w += x0 * wx0.w + x1 * wx1.w + x2 * wx2.w;
            float ig = 1.f / (1.f + expf(-s.x));
            float fg = 1.f / (1.f + expf(-s.y));
            float gg = tanhf(s.z);
            float og = 1.f / (1.f + expf(-s.w));
            cell = fg * cell + ig * gg;
            float hval = og * tanhf(cell);
            st_scf(hAcur + (size_t)j * BB + b, hval);
        }
        asm volatile("s_waitcnt vmcnt(0)" ::: "memory");
        __syncthreads();
        if (tid == 0) st_u(h_ep + g * 16, (unsigned)(t + 1));
        if (tid < 64) esampH = ld_u(h_ep + (bblk * 64 + tid) * 16);   // prefetch sample

        // ================= phase B(t) =================
        if (tid < 64) {
            const unsigned* p = h_ep + (bblk * 64 + tid) * 16;
            unsigned e = esampH;
            while (e < (unsigned)(t + 1)) { __builtin_amdgcn_s_sleep(1); e = ld_u(p); }
        }
        __syncthreads();
        asm volatile("" ::: "memory");

        // issue column load(s) first, then next-step staging (loads retire in order)
        float hcv = ld_scf(hAcur + (size_t)tid * BB + pb);
        const bool nllNow = (!isAttn) && (t > 0);
        float wcv = 0.f;
        if (nllNow && tid < 80)
            wcv = ld_scf(ws + (((t - 1) & 1) ? OFF_WT1 : OFF_WT0) + (size_t)tid * BB + pb);
        if (t < TSTEPS - 1) {
            #pragma unroll
            for (int i = 0; i < 16; ++i) {
                int lin = i * 512 + tid, d = lin >> 4, c2 = lin & 15;
                hr[i] = ld_sc2(hAcur + (size_t)d * BB + gb0 + c2 * 2);
            }
        }
        s_hcol[tid] = hcv;
        if (nllNow && tid < 80) s_wp[tid] = wcv;
        __syncthreads();

        if (isAttn) {
            float* wTc = ws + ((t & 1) ? OFF_WT1 : OFF_WT0);
            int m = tid & 31, seg = tid >> 5;
            if (m < 30) {
                const float4* hb4 = (const float4*)(s_hcol + seg * 32);
                float acc = 0.f;
                #pragma unroll
                for (int q = 0; q < 8; ++q) {
                    float4 h4 = hb4[q], w4 = wa[q];
                    acc = fmaf(h4.x, w4.x, acc); acc = fmaf(h4.y, w4.y, acc);
                    acc = fmaf(h4.z, w4.z, acc); acc = fmaf(h4.w, w4.w, acc);
                }
                s_pA[seg * 32 + m] = acc;
            }
            __syncthreads();
            if (tid < 30) {
                float v = b_att[tid];
                #pragma unroll
                for (int o = 0; o < 16; ++o) v += s_pA[o * 32 + tid];
                s_ab[tid] = v;
            }
            __syncthreads();
            float mk = seq_mask[(size_t)t * BB + pb];
            if (tid < NATT) {
                float ah = s_ab[tid], bh = s_ab[10 + tid], kh = s_ab[20 + tid];
                float kprev = s_kk[tid];
                float kn = kprev + __expf(kh);
                s_ab[32 + tid] = __expf(ah);
                s_ab[42 + tid] = __expf(bh);
                s_ab[52 + tid] = kn;
                s_kk[tid] = mk * kn + (1.f - mk) * kprev;
            }
            __syncthreads();
            if (tid < UU) {
                float uu = (float)tid, phi = 0.f;
                #pragma unroll
                for (int a = 0; a < NATT; ++a) {
                    float diff = s_ab[52 + a] - uu;
                    phi = fmaf(s_ab[32 + a], __expf(-s_ab[42 + a] * diff * diff), phi);
                }
                s_phi[tid] = phi * c_mask[(size_t)tid * BB + pb];
            }
            __syncthreads();
            if (tid < NCH) {
                float wn = 0.f;
                #pragma unroll 4
                for (int u = 0; u < UU; ++u)
                    wn += (s_ci[u] == tid) ? s_phi[u] : 0.f;
                float wnew = mk * wn + (1.f - mk) * s_wold[tid];
                s_wold[tid] = wnew;
                st_scf(wTc + (size_t)tid * BB + pb, wnew);
            }
            asm volatile("s_waitcnt vmcnt(0)" ::: "memory");
            __syncthreads();
            if (tid == 0) st_u(w_ep + (bblk * 32 + jblk) * 16, (unsigned)(t + 1));
        } else {
            if (nllNow) do_nll(t - 1);
            // yh(t) from own column, kept local in s_yh
            if (tid < 484) {
                int m = tid >> 2, qf = tid & 3;
                const float4* wm4 = (const float4*)(W_mix + (size_t)m * 592 + qf * 128);
                const float4* hc4 = (const float4*)(s_hcol + qf * 128);
                float acc = 0.f;
                #pragma unroll 8
                for (int d4 = 0; d4 < 32; ++d4) {
                    float4 h = hc4[d4], w = wm4[d4];
                    acc = fmaf(h.x, w.x, acc); acc = fmaf(h.y, w.y, acc);
                    acc = fmaf(h.z, w.z, acc); acc = fmaf(h.w, w.w, acc);
                }
                s_pA[tid] = acc;
            }
            __syncthreads();
            if (tid < 121)
                s_yh[tid] = s_pA[4 * tid] + s_pA[4 * tid + 1] + s_pA[4 * tid + 2] + s_pA[4 * tid + 3];
            __syncthreads();
        }
    }

    // ================= epilogue: NLL(1023) + reduction (mixture WGs) =================
    if (!isAttn) {
        if (tid == 0) {
            const unsigned* p = w_ep + (bblk * 32 + pbcol) * 16;
            while (ld_u(p) < (unsigned)TSTEPS) __builtin_amdgcn_s_sleep(2);
        }
        __syncthreads();
        asm volatile("" ::: "memory");
        if (tid < 80)
            s_wp[tid] = ld_scf(ws + (((TSTEPS - 1) & 1) ? OFF_WT1 : OFF_WT0) + (size_t)tid * BB + pb);
        __syncthreads();
        do_nll(TSTEPS - 1);
        if (tid == 0) {
            st_scf(red + pb, nll_acc);
            st_scf(red + BB + pb, mask_acc);
        }
        asm volatile("s_waitcnt vmcnt(0)" ::: "memory");
        __syncthreads();
        if (tid == 0)
            __hip_atomic_fetch_add(red_cnt, 1u, __ATOMIC_RELAXED, __HIP_MEMORY_SCOPE_AGENT);
    }
    if (g == 0 && tid == 0) {
        while (ld_u(red_cnt) < 128u) __builtin_amdgcn_s_sleep(2);
        asm volatile("" ::: "memory");
        float sn = 0.f, sm = 0.f;
        for (int i = 0; i < BB; ++i) { sn += ld_scf(red + i); sm += ld_scf(red + BB + i); }
        out[0] = sn / sm;
    }
}

extern "C" void kernel_launch(void* const* d_in, const int* in_sizes, int n_in,
                              void* d_out, int out_size, void* d_ws, size_t ws_size,
                              hipStream_t stream) {
    (void)in_sizes; (void)n_in; (void)out_size; (void)ws_size;
    const float* seq_pt   = (const float*)d_in[0];
    const float* seq_mask = (const float*)d_in[1];
    const float* tgt      = (const float*)d_in[2];
    const int*   cidx     = (const int*)d_in[3];
    const float* c_mask   = (const float*)d_in[4];
    const float* W_ih     = (const float*)d_in[5];
    const float* b_ih     = (const float*)d_in[6];
    const float* W_hh     = (const float*)d_in[7];
    const float* b_hh     = (const float*)d_in[8];
    const float* W_att    = (const float*)d_in[9];
    const float* b_att    = (const float*)d_in[10];
    const float* W_mix    = (const float*)d_in[11];
    const float* b_mix    = (const float*)d_in[12];
    float* out = (float*)d_out;
    float* ws  = (float*)d_ws;

    hipLaunchKernelGGL(init_sync_kernel, dim3(1), dim3(256), 0, stream, ws);
    hipLaunchKernelGGL(hw_kernel, dim3(256), dim3(512), 0, stream,
                       seq_pt, seq_mask, tgt, cidx, c_mask,
                       W_ih, b_ih, W_hh, b_hh, W_att, b_att,
                       W_mix, b_mix, out, ws);
}

// Round 11
// 21488.667 us; speedup vs baseline: 7.9848x; 7.9848x over previous
//
#include <hip/hip_runtime.h>

#define TSTEPS 1024
#define BB 128
#define HH 512
#define NCH 80
#define NATT 10
#define NG 20
#define UU 64
#define LOG2PI 1.8378770664093453f

// ws float offsets
#define OFF_HA0 0
#define OFF_HA1 65536
#define OFF_HB0 131072
#define OFF_HB1 196608
#define OFF_WT0 262144
#define OFF_WT1 272384
#define OFF_RED 282624
#define OFF_EP  282880      // h_ep[256]*16 | b_ep[128]*16 | red_cnt
#define EP_WORDS (256*16 + 128*16 + 16)

static __device__ __forceinline__ float ld_scf(const float* p) {
    return __hip_atomic_load((float*)p, __ATOMIC_RELAXED, __HIP_MEMORY_SCOPE_AGENT);
}
static __device__ __forceinline__ void st_scf(float* p, float v) {
    __hip_atomic_store(p, v, __ATOMIC_RELAXED, __HIP_MEMORY_SCOPE_AGENT);
}
static __device__ __forceinline__ float2 ld_sc2(const float* p) {
    unsigned long long v = __hip_atomic_load((unsigned long long*)p, __ATOMIC_RELAXED, __HIP_MEMORY_SCOPE_AGENT);
    float2 f; __builtin_memcpy(&f, &v, 8); return f;
}
static __device__ __forceinline__ unsigned ld_u(const unsigned* p) {
    return __hip_atomic_load((unsigned*)p, __ATOMIC_RELAXED, __HIP_MEMORY_SCOPE_AGENT);
}
static __device__ __forceinline__ void st_u(unsigned* p, unsigned v) {
    __hip_atomic_store(p, v, __ATOMIC_RELAXED, __HIP_MEMORY_SCOPE_AGENT);
}

__global__ void init_sync_kernel(float* ws) {
    unsigned* s = (unsigned*)(ws + OFF_EP);
    for (int i = threadIdx.x; i < EP_WORDS; i += blockDim.x) st_u(s + i, 0u);
}

__global__ __launch_bounds__(512)
void hw_kernel(const float* __restrict__ seq_pt, const float* __restrict__ seq_mask,
               const float* __restrict__ tgt, const int* __restrict__ cidx,
               const float* __restrict__ c_mask,
               const float* __restrict__ W_ih, const float* __restrict__ b_ih,
               const float* __restrict__ W_hh, const float* __restrict__ b_hh,
               const float* __restrict__ W_att, const float* __restrict__ b_att,
               const float* __restrict__ W_mix, const float* __restrict__ b_mix,
               float* __restrict__ out, float* __restrict__ ws)
{
    const int g = blockIdx.x;
    const int tid = threadIdx.x;
    const int jblk = g >> 2;            // 0..63 (8 hidden units)
    const int bblk = g & 3;             // 0..3  (32 batches)
    const int gb0 = bblk * 32;
    const bool isAttn = (jblk < 32);
    const int pbcol = isAttn ? jblk : (jblk - 32);
    const int pb = gb0 + pbcol;         // phase-B / NLL batch
    const int jj  = tid & 7;
    const int bg3 = (tid >> 3) & 7;
    const int ks  = tid >> 6;           // wave index (0..7) = d-split

    __shared__ float4 s_wW[8][601];              // 76.9 KB gate weights
    __shared__ __align__(16) float s_chm[9216];  // 36.9 KB: 3 chunk buffers; phase-B column overlay
    __shared__ __align__(16) float s_part[10240];// 40 KB partials [512][20]
    __shared__ float s_pA[512];
    __shared__ float s_ab[72];
    __shared__ float s_kk[16], s_wold[NCH], s_phi[UU];
    __shared__ int   s_ci[UU];
    __shared__ float s_yh[124], s_wp[84];
    __shared__ float s_y[124], s_nA[20], s_nB[20], s_pen[1];

    // ---- persistent LDS gate weights ----
    for (int lin = tid; lin < 8 * 596; lin += 512) {
        int lj = lin / 596, idx = lin % 596;
        int jg = jblk * 8 + lj;
        float4 v;
        if (idx < 512) {
            v = make_float4(W_hh[(0 * HH + jg) * HH + idx], W_hh[(1 * HH + jg) * HH + idx],
                            W_hh[(2 * HH + jg) * HH + idx], W_hh[(3 * HH + jg) * HH + idx]);
        } else if (idx < 592) {
            int dd = 3 + (idx - 512);
            v = make_float4(W_ih[(0 * HH + jg) * 83 + dd], W_ih[(1 * HH + jg) * 83 + dd],
                            W_ih[(2 * HH + jg) * 83 + dd], W_ih[(3 * HH + jg) * 83 + dd]);
        } else if (idx < 595) {
            int dd = idx - 592;
            v = make_float4(W_ih[(0 * HH + jg) * 83 + dd], W_ih[(1 * HH + jg) * 83 + dd],
                            W_ih[(2 * HH + jg) * 83 + dd], W_ih[(3 * HH + jg) * 83 + dd]);
        } else {
            v = make_float4(b_ih[0 * HH + jg] + b_hh[0 * HH + jg], b_ih[1 * HH + jg] + b_hh[1 * HH + jg],
                            b_ih[2 * HH + jg] + b_hh[2 * HH + jg], b_ih[3 * HH + jg] + b_hh[3 * HH + jg]);
        }
        s_wW[lj][idx] = v;
    }
    if (isAttn && tid < UU) s_ci[tid] = cidx[(size_t)tid * BB + pb];
    if (tid < 16) s_kk[tid] = 0.f;
    if (tid < NCH) s_wold[tid] = 0.f;
    __syncthreads();

    unsigned* h_ep = (unsigned*)(ws + OFF_EP);
    unsigned* b_ep = h_ep + 256 * 16;
    unsigned* red_cnt = b_ep + 128 * 16;
    float* red = ws + OFF_RED;

    float cell = 0.f, nll_acc = 0.f, mask_acc = 0.f;
    unsigned esampH = 0;

    auto FMA4 = [](float4& acc, float h, float4 w) {
        acc.x = fmaf(h, w.x, acc.x); acc.y = fmaf(h, w.y, acc.y);
        acc.z = fmaf(h, w.z, acc.z); acc.w = fmaf(h, w.w, acc.w);
    };

    // NLL(tp) on mixture WGs: s_yh = yh(tp) (local), s_wp = w(tp) column
    auto do_nll = [&](int tp) {
        if (tid < 121) {
            const float* wm = W_mix + (size_t)tid * 592 + 512;   // cached read-only
            float acc = s_yh[tid] + b_mix[tid];
            #pragma unroll 8
            for (int c = 0; c < NCH; ++c) acc = fmaf(s_wp[c], wm[c], acc);
            s_y[tid] = acc;
        }
        __syncthreads();
        if (tid < 21) {
            const float* tg = tgt + ((size_t)tp * BB + pb) * 3;
            if (tid < NG) {
                int m = tid;
                float y0 = s_y[m], y1 = s_y[20 + m], y2 = s_y[40 + m];
                float y3 = s_y[60 + m], y4 = s_y[80 + m], y5 = s_y[100 + m];
                float x1 = tg[0], x2 = tg[1];
                float rho = tanhf(y5);
                float d1 = (x1 - y1) * expf(-y3);
                float d2 = (x2 - y2) * expf(-y4);
                float omr2 = 1.f - rho * rho;
                float Z = d1 * d1 + d2 * d2 - 2.f * rho * d1 * d2;
                float log_n = -Z / (2.f * omr2) - LOG2PI - y3 - y4 - 0.5f * logf(omr2);
                s_nA[m] = y0;
                s_nB[m] = y0 + log_n;
            } else {
                float yp = s_y[120];
                float pen = tg[2];
                float e = log1pf(expf(-fabsf(yp)));
                float ls_p = fminf(yp, 0.f) - e;
                float ls_n = fminf(-yp, 0.f) - e;
                s_pen[0] = -(pen * ls_p + (1.f - pen) * ls_n);
            }
        }
        __syncthreads();
        if (tid == 0) {
            float mx1 = -1e30f, mx2 = -1e30f;
            for (int m = 0; m < NG; ++m) { mx1 = fmaxf(mx1, s_nA[m]); mx2 = fmaxf(mx2, s_nB[m]); }
            float se1 = 0.f, se2 = 0.f;
            for (int m = 0; m < NG; ++m) { se1 += expf(s_nA[m] - mx1); se2 += expf(s_nB[m] - mx2); }
            float nll = (mx1 + logf(se1)) - (mx2 + logf(se2)) + s_pen[0];
            float mk = seq_mask[(size_t)tp * BB + pb];
            nll_acc += mk * nll;
            mask_acc += mk;
        }
        __syncthreads();
    };

    for (int t = 0; t < TSTEPS; ++t) {
        float* hAcur = ws + ((t & 1) ? OFF_HA1 : OFF_HA0);
        const float* hAprv = ws + ((t & 1) ? OFF_HA0 : OFF_HA1);
        float* hBcur = ws + ((t & 1) ? OFF_HB1 : OFF_HB0);
        const float* wTprv = ws + (((t ^ 1) & 1) ? OFF_WT1 : OFF_WT0);   // (t-1)&1 parity
        float* wTcur = ws + ((t & 1) ? OFF_WT1 : OFF_WT0);

        // ======== phase A(t): chunked staging + gate GEMM ========
        float4 a0 = make_float4(0.f,0.f,0.f,0.f), a1 = a0, a2 = a0, a3 = a0;

        if (t > 0) {
            float2 rgA[4], rgB[4];
            auto stage_issue = [&](int r, float2* rg) {
                if (r < 6) {
                    #pragma unroll
                    for (int i = 0; i < 3; ++i) {
                        int lin = i * 512 + tid;
                        int dR = lin >> 4, c2 = lin & 15;
                        int R = r * 96 + dR;
                        const float* src = (R < 512) ? (hAprv + (size_t)R * BB)
                                                     : (wTprv + (size_t)(R - 512) * BB);
                        rg[i] = ld_sc2(src + gb0 + c2 * 2);
                    }
                } else if (tid < 256) {
                    int dR = tid >> 4, c2 = tid & 15;
                    rg[0] = ld_sc2(wTprv + (size_t)(64 + dR) * BB + gb0 + c2 * 2);
                }
            };
            auto stage_write = [&](int r, const float2* rg) {
                float* bufp = s_chm + (r % 3) * 3072;
                if (r < 6) {
                    #pragma unroll
                    for (int i = 0; i < 3; ++i) {
                        int lin = i * 512 + tid;
                        int dR = lin >> 4, c2 = lin & 15;
                        ((float2*)bufp)[dR * 16 + c2] = rg[i];
                    }
                } else if (tid < 256) {
                    int dR = tid >> 4, c2 = tid & 15;
                    ((float2*)bufp)[dR * 16 + c2] = rg[0];
                }
            };
            auto fma_rows = [&](const float* cb, int rb, int wb, int nd) {
                #pragma unroll 4
                for (int dl = 0; dl < nd; ++dl) {
                    float4 wv = s_wW[jj][wb + dl];
                    float4 hv = *(const float4*)&cb[(rb + dl) * 32 + bg3 * 4];
                    FMA4(a0, hv.x, wv); FMA4(a1, hv.y, wv);
                    FMA4(a2, hv.z, wv); FMA4(a3, hv.w, wv);
                }
            };

            // wait h(t-1) from my bblk-group
            if (tid < 64) {
                const unsigned* p = h_ep + (bblk * 64 + tid) * 16;
                unsigned e = esampH;
                while (e < (unsigned)t) { __builtin_amdgcn_s_sleep(1); e = ld_u(p); }
            }
            __syncthreads();
            asm volatile("" ::: "memory");

            stage_issue(0, rgA);
            stage_issue(1, rgB);
            stage_write(0, rgA);
            __syncthreads();
            #pragma unroll 1
            for (int r = 0; r < 7; ++r) {
                if (r == 3) {   // w(t-1) needed from chunk-5 issue on (published end of B(t-1))
                    if (tid < 32) {
                        const unsigned* p = b_ep + (bblk * 32 + tid) * 16;
                        while (ld_u(p) < (unsigned)t) __builtin_amdgcn_s_sleep(1);
                    }
                    __syncthreads();
                    asm volatile("" ::: "memory");
                }
                if (r + 2 <= 6) stage_issue(r + 2, (r & 1) ? rgB : rgA);
                if (r + 1 <= 6) stage_write(r + 1, ((r + 1) & 1) ? rgB : rgA);
                __syncthreads();
                const float* cb = s_chm + (r % 3) * 3072;
                if (r < 6) fma_rows(cb, ks * 12, r * 96 + ks * 12, 12);
                else       fma_rows(cb, ks * 2, 576 + ks * 2, 2);
            }
            {   // partial exchange, pitch-20 (bank-spread)
                int R = ((ks * 8 + jj) << 3) + bg3;
                *(float4*)&s_part[R * 20 + 0]  = a0;
                *(float4*)&s_part[R * 20 + 4]  = a1;
                *(float4*)&s_part[R * 20 + 8]  = a2;
                *(float4*)&s_part[R * 20 + 12] = a3;
            }
        }
        __syncthreads();

        // pointwise LSTM: tid<256, thread = (j, b); write hA (for staging) + hB (for columns)
        if (tid < 256) {
            const int jj_o = tid >> 5, bl = tid & 31;
            const int b = gb0 + bl, j = jblk * 8 + jj_o;
            float4 s = s_wW[jj_o][595];  // fused bias
            if (t > 0) {
                #pragma unroll
                for (int k2 = 0; k2 < 8; ++k2) {
                    int Rr = ((k2 * 8 + jj_o) << 3) + (bl >> 2);
                    float4 v = *(const float4*)&s_part[Rr * 20 + (bl & 3) * 4];
                    s.x += v.x; s.y += v.y; s.z += v.z; s.w += v.w;
                }
            }
            const float* ip = seq_pt + ((size_t)t * BB + b) * 3;
            float x0 = ip[0], x1 = ip[1], x2 = ip[2];
            float4 wx0 = s_wW[jj_o][592], wx1 = s_wW[jj_o][593], wx2 = s_wW[jj_o][594];
            s.x += x0 * wx0.x + x1 * wx1.x + x2 * wx2.x;
            s.y += x0 * wx0.y + x1 * wx1.y + x2 * wx2.y;
            s.z += x0 * wx0.z + x1 * wx1.z + x2 * wx2.z;
            s.w += x0 * wx0.w + x1 * wx1.w + x2 * wx2.w;
            float ig = 1.f / (1.f + expf(-s.x));
            float fg = 1.f / (1.f + expf(-s.y));
            float gg = tanhf(s.z);
            float og = 1.f / (1.f + expf(-s.w));
            cell = fg * cell + ig * gg;
            float hval = og * tanhf(cell);
            st_scf(hAcur + (size_t)j * BB + b, hval);
            st_scf(hBcur + (size_t)b * HH + j, hval);
        }
        asm volatile("s_waitcnt vmcnt(0)" ::: "memory");
        __syncthreads();
        if (tid == 0) st_u(h_ep + g * 16, (unsigned)(t + 1));   // h(t) published
        if (tid < 64) esampH = ld_u(h_ep + (bblk * 64 + tid) * 16);

        // ---- NLL(t-1) on mixture WGs (off chain; w(t-1) visibility by phase-A w-wait) ----
        if (!isAttn && t > 0) {
            if (tid < 80) s_wp[tid] = ld_scf(wTprv + (size_t)tid * BB + pb);
            __syncthreads();
            do_nll(t - 1);
        }

        // ======== phase B(t) ========
        if (tid < 64) {
            const unsigned* p = h_ep + (bblk * 64 + tid) * 16;
            unsigned e = esampH;
            while (e < (unsigned)(t + 1)) { __builtin_amdgcn_s_sleep(1); e = ld_u(p); }
        }
        __syncthreads();
        asm volatile("" ::: "memory");
        {
            float* s_h = s_chm;
            if (tid < 256) ((float2*)s_h)[tid] = ld_sc2(hBcur + (size_t)pb * HH + tid * 2);
            __syncthreads();
            float mk = seq_mask[(size_t)t * BB + pb];
            if (isAttn) {
                int m = tid & 31, seg = tid >> 5;    // 16 segments x 32 d
                if (m < 30) {
                    const float* wa = W_att + (size_t)m * HH + seg * 32;
                    const float* hb = s_h + seg * 32;
                    float acc = 0.f;
                    #pragma unroll 8
                    for (int d = 0; d < 32; ++d) acc = fmaf(hb[d], wa[d], acc);
                    s_pA[seg * 32 + m] = acc;
                }
                __syncthreads();
                if (tid < 30) {
                    float v = b_att[tid];
                    #pragma unroll
                    for (int o = 0; o < 16; ++o) v += s_pA[o * 32 + tid];
                    s_ab[tid] = v;
                }
                __syncthreads();
                if (tid < NATT) {
                    float ah = s_ab[tid], bh = s_ab[10 + tid], kh = s_ab[20 + tid];
                    float kprev = s_kk[tid];
                    float kn = kprev + __expf(kh);
                    s_ab[32 + tid] = __expf(ah);
                    s_ab[42 + tid] = __expf(bh);
                    s_ab[52 + tid] = kn;
                    s_kk[tid] = mk * kn + (1.f - mk) * kprev;
                }
                __syncthreads();
                if (tid < UU) {
                    float uu = (float)tid, phi = 0.f;
                    #pragma unroll
                    for (int a = 0; a < NATT; ++a) {
                        float diff = s_ab[52 + a] - uu;
                        phi = fmaf(s_ab[32 + a], __expf(-s_ab[42 + a] * diff * diff), phi);
                    }
                    s_phi[tid] = phi * c_mask[(size_t)tid * BB + pb];
                }
                __syncthreads();
                if (tid < NCH) {
                    float wn = 0.f;
                    #pragma unroll 4
                    for (int u = 0; u < UU; ++u)
                        wn += (s_ci[u] == tid) ? s_phi[u] : 0.f;
                    float wnew = mk * wn + (1.f - mk) * s_wold[tid];
                    s_wold[tid] = wnew;
                    st_scf(wTcur + (size_t)tid * BB + pb, wnew);
                }
                asm volatile("s_waitcnt vmcnt(0)" ::: "memory");
                __syncthreads();
                if (tid == 0) st_u(b_ep + (bblk * 32 + jblk) * 16, (unsigned)(t + 1));
            } else {
                // yh(t) for own batch, kept local
                if (tid < 484) {
                    int m = tid >> 2, qf = tid & 3;
                    const float* wm = W_mix + (size_t)m * 592 + qf * 128;
                    const float* hb = s_h + qf * 128;
                    float acc = 0.f;
                    #pragma unroll 8
                    for (int d = 0; d < 128; ++d) acc = fmaf(hb[d], wm[d], acc);
                    s_pA[tid] = acc;
                }
                __syncthreads();
                if (tid < 121)
                    s_yh[tid] = s_pA[4 * tid] + s_pA[4 * tid + 1] + s_pA[4 * tid + 2] + s_pA[4 * tid + 3];
                __syncthreads();
            }
        }
    }

    // ======== epilogue: NLL(1023) + reduction (mixture WGs) ========
    if (!isAttn) {
        if (tid == 0) {
            const unsigned* p = b_ep + (bblk * 32 + pbcol) * 16;
            while (ld_u(p) < (unsigned)TSTEPS) __builtin_amdgcn_s_sleep(2);
        }
        __syncthreads();
        asm volatile("" ::: "memory");
        if (tid < 80)
            s_wp[tid] = ld_scf(ws + (((TSTEPS - 1) & 1) ? OFF_WT1 : OFF_WT0) + (size_t)tid * BB + pb);
        __syncthreads();
        do_nll(TSTEPS - 1);
        if (tid == 0) {
            st_scf(red + pb, nll_acc);
            st_scf(red + BB + pb, mask_acc);
        }
        asm volatile("s_waitcnt vmcnt(0)" ::: "memory");
        __syncthreads();
        if (tid == 0)
            __hip_atomic_fetch_add(red_cnt, 1u, __ATOMIC_RELAXED, __HIP_MEMORY_SCOPE_AGENT);
    }
    if (g == 0 && tid == 0) {
        while (ld_u(red_cnt) < 128u) __builtin_amdgcn_s_sleep(2);
        asm volatile("" ::: "memory");
        float sn = 0.f, sm = 0.f;
        for (int i = 0; i < BB; ++i) { sn += ld_scf(red + i); sm += ld_scf(red + BB + i); }
        out[0] = sn / sm;
    }
}

extern "C" void kernel_launch(void* const* d_in, const int* in_sizes, int n_in,
                              void* d_out, int out_size, void* d_ws, size_t ws_size,
                              hipStream_t stream) {
    (void)in_sizes; (void)n_in; (void)out_size; (void)ws_size;
    const float* seq_pt   = (const float*)d_in[0];
    const float* seq_mask = (const float*)d_in[1];
    const float* tgt      = (const float*)d_in[2];
    const int*   cidx     = (const int*)d_in[3];
    const float* c_mask   = (const float*)d_in[4];
    const float* W_ih     = (const float*)d_in[5];
    const float* b_ih     = (const float*)d_in[6];
    const float* W_hh     = (const float*)d_in[7];
    const float* b_hh     = (const float*)d_in[8];
    const float* W_att    = (const float*)d_in[9];
    const float* b_att    = (const float*)d_in[10];
    const float* W_mix    = (const float*)d_in[11];
    const float* b_mix    = (const float*)d_in[12];
    float* out = (float*)d_out;
    float* ws  = (float*)d_ws;

    hipLaunchKernelGGL(init_sync_kernel, dim3(1), dim3(256), 0, stream, ws);
    hipLaunchKernelGGL(hw_kernel, dim3(256), dim3(512), 0, stream,
                       seq_pt, seq_mask, tgt, cidx, c_mask,
                       W_ih, b_ih, W_hh, b_hh, W_att, b_att,
                       W_mix, b_mix, out, ws);
}